// Round 1
// baseline (768.972 us; speedup 1.0000x reference)
//
#include <hip/hip_runtime.h>
#include <hip/hip_bf16.h>
#include <stdint.h>

#define NEG_F (-4294967295.0f)

typedef __attribute__((ext_vector_type(4))) float  floatx4;
typedef __attribute__((ext_vector_type(8))) short  shortx8;

__device__ __forceinline__ unsigned short f2bf(float f) {
    unsigned int u = __builtin_bit_cast(unsigned int, f);
    u += 0x7FFFu + ((u >> 16) & 1u);
    return (unsigned short)(u >> 16);
}

__device__ __forceinline__ uint4 pack8(float4 a, float4 b) {
    uint4 r;
    r.x = (unsigned)f2bf(a.x) | ((unsigned)f2bf(a.y) << 16);
    r.y = (unsigned)f2bf(a.z) | ((unsigned)f2bf(a.w) << 16);
    r.z = (unsigned)f2bf(b.x) | ((unsigned)f2bf(b.y) << 16);
    r.w = (unsigned)f2bf(b.z) | ((unsigned)f2bf(b.w) << 16);
    return r;
}

// ---------------- cast kernels ----------------
__global__ __launch_bounds__(256) void cast_bf16(const float* __restrict__ src,
                                                 ushort* __restrict__ dst) {
    long long i = ((long long)blockIdx.x * 256 + threadIdx.x) * 8;
    const float4* p = (const float4*)(src + i);
    float4 f0 = p[0], f1 = p[1];
    *(uint4*)(dst + i) = pack8(f0, f1);
}

// decoder (8192x1024 fp32) -> concat left half (row stride 2048, bf16)
__global__ __launch_bounds__(256) void cast_stride(const float* __restrict__ src,
                                                   ushort* __restrict__ dst) {
    long long i = ((long long)blockIdx.x * 256 + threadIdx.x) * 8;
    long long r = i >> 10, c = i & 1023;
    const float4* p = (const float4*)(src + i);
    float4 f0 = p[0], f1 = p[1];
    *(uint4*)(dst + r * 2048 + c) = pack8(f0, f1);
}

// ---------------- weight transpose-cast: W[K][N] fp32 -> WT[N][K] bf16 ----------------
__global__ __launch_bounds__(256) void wtrans(const float* __restrict__ W,
                                              ushort* __restrict__ WT, int K, int N) {
    __shared__ float t[32][33];
    int tx = threadIdx.x, ty = threadIdx.y;
    int bx = blockIdx.x * 32;  // n
    int by = blockIdx.y * 32;  // k
    #pragma unroll
    for (int i = 0; i < 4; i++)
        t[ty + 8 * i][tx] = W[(size_t)(by + ty + 8 * i) * N + bx + tx];
    __syncthreads();
    #pragma unroll
    for (int i = 0; i < 4; i++)
        WT[(size_t)(bx + ty + 8 * i) * K + by + tx] = f2bf(t[tx][ty + 8 * i]);
}

// ---------------- V transpose per (b,h): V[(b*1024+k)*1024+h*128+d] -> VT[((h*8+b)*128+d)*1024+k]
__global__ __launch_bounds__(256) void vtrans(const ushort* __restrict__ V,
                                              ushort* __restrict__ VT) {
    __shared__ ushort t[32][33];
    int tx = threadIdx.x, ty = threadIdx.y;
    int bk = blockIdx.x * 32;  // k
    int bd = blockIdx.y * 32;  // d
    int z = blockIdx.z;
    int b = z >> 3, h = z & 7;
    #pragma unroll
    for (int i = 0; i < 4; i++)
        t[ty + 8 * i][tx] = V[((size_t)(b * 1024 + bk + ty + 8 * i)) * 1024 + h * 128 + bd + tx];
    __syncthreads();
    #pragma unroll
    for (int i = 0; i < 4; i++)
        VT[((size_t)((h * 8 + b) * 128 + bd + ty + 8 * i)) * 1024 + bk + tx] = t[tx][ty + 8 * i];
}

// ---------------- batched GEMM: C[m][n] = alpha * sum_k A[m][k] * Bt[n][k] ----------------
// 128x128 block tile, 4 waves (each 64x64 via 4x4 of 16x16x32 MFMA), BK=64.
template <typename TA, typename TC>
__global__ __launch_bounds__(256) void gemm_bt(
    const TA* __restrict__ A, const ushort* __restrict__ Bt, TC* __restrict__ C,
    int K, int lda, int ldb, int ldc, int zdiv,
    long long sA1, long long sA2, long long sB1, long long sB2,
    long long sC1, long long sC2, float alpha) {
    constexpr int LS = 72;  // padded LDS K-stride (elements)
    __shared__ ushort As[128 * LS];
    __shared__ ushort Bs[128 * LS];

    int z = blockIdx.z;
    int z1 = z / zdiv, z2 = z % zdiv;
    const TA* Ab = A + (long long)z1 * sA1 + (long long)z2 * sA2;
    const ushort* Bb = Bt + (long long)z1 * sB1 + (long long)z2 * sB2;
    TC* Cb = C + (long long)z1 * sC1 + (long long)z2 * sC2;

    int tid = threadIdx.x;
    int bm = blockIdx.y * 128, bn = blockIdx.x * 128;
    int l = tid & 63, wid = tid >> 6;
    int l16 = l & 15, quad = l >> 4;
    int wm = (wid & 1) * 64, wn = (wid >> 1) * 64;

    floatx4 acc[4][4];
    #pragma unroll
    for (int i = 0; i < 4; i++)
        #pragma unroll
        for (int j = 0; j < 4; j++)
            acc[i][j] = {0.0f, 0.0f, 0.0f, 0.0f};

    for (int kt = 0; kt < K; kt += 64) {
        // stage A tile (128x64) and B tile (128x64) into LDS as bf16
        #pragma unroll
        for (int it = 0; it < 4; it++) {
            int lin = it * 256 + tid;
            int row = lin >> 3, col = (lin & 7) << 3;
            uint4 av;
            if constexpr (__is_same(TA, float)) {
                const float4* p = (const float4*)(Ab + (size_t)(bm + row) * lda + kt + col);
                av = pack8(p[0], p[1]);
            } else {
                av = *(const uint4*)(Ab + (size_t)(bm + row) * lda + kt + col);
            }
            *(uint4*)&As[row * LS + col] = av;
            uint4 bv = *(const uint4*)(Bb + (size_t)(bn + row) * ldb + kt + col);
            *(uint4*)&Bs[row * LS + col] = bv;
        }
        __syncthreads();
        #pragma unroll
        for (int kk = 0; kk < 64; kk += 32) {
            shortx8 af[4], bfr[4];
            #pragma unroll
            for (int i = 0; i < 4; i++)
                af[i] = *(const shortx8*)&As[(wm + i * 16 + l16) * LS + kk + quad * 8];
            #pragma unroll
            for (int j = 0; j < 4; j++)
                bfr[j] = *(const shortx8*)&Bs[(wn + j * 16 + l16) * LS + kk + quad * 8];
            #pragma unroll
            for (int i = 0; i < 4; i++)
                #pragma unroll
                for (int j = 0; j < 4; j++)
                    acc[i][j] = __builtin_amdgcn_mfma_f32_16x16x32_bf16(af[i], bfr[j], acc[i][j], 0, 0, 0);
        }
        __syncthreads();
    }

    // epilogue: D row = quad*4 + reg, col = l16 within each 16x16 tile
    #pragma unroll
    for (int i = 0; i < 4; i++) {
        #pragma unroll
        for (int j = 0; j < 4; j++) {
            int row0 = bm + wm + i * 16 + quad * 4;
            int col = bn + wn + j * 16 + l16;
            #pragma unroll
            for (int r = 0; r < 4; r++) {
                float v = acc[i][j][r] * alpha;
                size_t idx = (size_t)(row0 + r) * ldc + col;
                if constexpr (__is_same(TC, float)) Cb[idx] = v;
                else Cb[idx] = f2bf(v);
            }
        }
    }
}

// ---------------- masked softmax + query-mask, in-place on fp32 scores ----------------
__global__ __launch_bounds__(256) void softmax_qm(float* __restrict__ attns,
                                                  const int* __restrict__ mask,
                                                  const float* __restrict__ qmask) {
    __shared__ float sb[4];
    int row = blockIdx.x;           // (h*8+b)*1024 + q
    int hb = row >> 10;
    int b = hb & 7;
    int q = row & 1023;
    float* srow = attns + (size_t)row * 1024;
    const int* mrow = mask + ((size_t)(b * 1024 + q)) * 1024;
    int tid = threadIdx.x;
    int k4 = tid * 4;

    float4 s = *(const float4*)(srow + k4);
    int4 m = *(const int4*)(mrow + k4);
    s.x = m.x ? NEG_F : s.x;
    s.y = m.y ? NEG_F : s.y;
    s.z = m.z ? NEG_F : s.z;
    s.w = m.w ? NEG_F : s.w;

    float mx = fmaxf(fmaxf(s.x, s.y), fmaxf(s.z, s.w));
    #pragma unroll
    for (int o = 32; o; o >>= 1) mx = fmaxf(mx, __shfl_down(mx, o, 64));
    if ((tid & 63) == 0) sb[tid >> 6] = mx;
    __syncthreads();
    mx = fmaxf(fmaxf(sb[0], sb[1]), fmaxf(sb[2], sb[3]));
    __syncthreads();

    float4 p;
    p.x = __expf(s.x - mx);
    p.y = __expf(s.y - mx);
    p.z = __expf(s.z - mx);
    p.w = __expf(s.w - mx);
    float sum = p.x + p.y + p.z + p.w;
    #pragma unroll
    for (int o = 32; o; o >>= 1) sum += __shfl_down(sum, o, 64);
    if ((tid & 63) == 0) sb[tid >> 6] = sum;
    __syncthreads();
    sum = sb[0] + sb[1] + sb[2] + sb[3];

    float scale = qmask[b * 1024 + q] / sum;
    p.x *= scale; p.y *= scale; p.z *= scale; p.w *= scale;
    *(float4*)(srow + k4) = p;
}

// ---------------- LayerNorm epilogue: x = LN(ffn + bf + decoder) ----------------
__global__ __launch_bounds__(256) void ln_out(const float* __restrict__ ffn,
                                              const float* __restrict__ dec,
                                              const float* __restrict__ bfv,
                                              const float* __restrict__ gamma,
                                              const float* __restrict__ beta,
                                              float* __restrict__ out) {
    __shared__ float sb[8];
    int row = blockIdx.x, tid = threadIdx.x;
    int c = tid * 4;
    size_t base = (size_t)row * 1024 + c;
    float4 x = *(const float4*)(ffn + base);
    float4 d = *(const float4*)(dec + base);
    float4 bb = *(const float4*)(bfv + c);
    x.x += d.x + bb.x; x.y += d.y + bb.y; x.z += d.z + bb.z; x.w += d.w + bb.w;

    float s = x.x + x.y + x.z + x.w;
    float s2 = x.x * x.x + x.y * x.y + x.z * x.z + x.w * x.w;
    #pragma unroll
    for (int o = 32; o; o >>= 1) {
        s += __shfl_down(s, o, 64);
        s2 += __shfl_down(s2, o, 64);
    }
    if ((tid & 63) == 0) { sb[tid >> 6] = s; sb[4 + (tid >> 6)] = s2; }
    __syncthreads();
    s = sb[0] + sb[1] + sb[2] + sb[3];
    s2 = sb[4] + sb[5] + sb[6] + sb[7];
    float mu = s * (1.0f / 1024.0f);
    float var = s2 * (1.0f / 1024.0f) - mu * mu;
    float rs = rsqrtf(var + 1e-5f);

    float4 g = *(const float4*)(gamma + c);
    float4 be = *(const float4*)(beta + c);
    float4 o4;
    o4.x = (x.x - mu) * rs * g.x + be.x;
    o4.y = (x.y - mu) * rs * g.y + be.y;
    o4.z = (x.z - mu) * rs * g.z + be.z;
    o4.w = (x.w - mu) * rs * g.w + be.w;
    *(float4*)(out + base) = o4;
}

extern "C" void kernel_launch(void* const* d_in, const int* in_sizes, int n_in,
                              void* d_out, int out_size, void* d_ws, size_t ws_size,
                              hipStream_t stream) {
    const float* memory  = (const float*)d_in[0];   // (8,1024,1024)
    const float* decoder = (const float*)d_in[1];   // (8,1024,1024)
    const float* qmask   = (const float*)d_in[2];   // (8,1024)
    const float* Wk      = (const float*)d_in[3];   // (1024,1024)
    const float* Wv      = (const float*)d_in[4];
    const float* Wq      = (const float*)d_in[5];
    const float* Wf      = (const float*)d_in[6];   // (2048,1024)
    const float* bfv     = (const float*)d_in[7];   // (1024,)
    const float* gamma   = (const float*)d_in[8];
    const float* beta    = (const float*)d_in[9];
    const int*   mask    = (const int*)d_in[10];    // (8,1024,1024) 0/1

    float* xout  = (float*)d_out;                   // (8,1024,1024)
    float* attns = xout + 8388608LL;                // (64,1024,1024)

    // workspace layout (122 MB); ffn (fp32 32MB) reuses mem_bf+Kp region
    char* w = (char*)d_ws;
    ushort* mem_bf = (ushort*)(w + 0);              // 16 MB (dead after projections)
    ushort* Kp     = (ushort*)(w + (16LL << 20));   // 16 MB (dead after scores)
    float*  ffn    = (float*)(w + 0);               // 32 MB, written after Kp dead
    ushort* Qp     = (ushort*)(w + (32LL << 20));   // 16 MB
    ushort* Vp     = (ushort*)(w + (48LL << 20));   // 16 MB
    ushort* VT     = (ushort*)(w + (64LL << 20));   // 16 MB
    ushort* concat = (ushort*)(w + (80LL << 20));   // 32 MB (8192 x 2048 bf16)
    ushort* WkT    = (ushort*)(w + (112LL << 20));  // 2 MB
    ushort* WvT    = (ushort*)(w + (114LL << 20));  // 2 MB
    ushort* WqT    = (ushort*)(w + (116LL << 20));  // 2 MB
    ushort* WfT    = (ushort*)(w + (118LL << 20));  // 4 MB

    const float alpha_s = 0.08838834764831845f;  // 1/sqrt(128)

    // 1) casts
    cast_bf16<<<4096, 256, 0, stream>>>(memory, mem_bf);
    cast_stride<<<4096, 256, 0, stream>>>(decoder, concat);
    // 2) weight transposes
    wtrans<<<dim3(32, 32), dim3(32, 8), 0, stream>>>(Wk, WkT, 1024, 1024);
    wtrans<<<dim3(32, 32), dim3(32, 8), 0, stream>>>(Wv, WvT, 1024, 1024);
    wtrans<<<dim3(32, 32), dim3(32, 8), 0, stream>>>(Wq, WqT, 1024, 1024);
    wtrans<<<dim3(32, 64), dim3(32, 8), 0, stream>>>(Wf, WfT, 2048, 1024);
    // 3) projections: K,V from memory; Q from decoder (concat left half, lda=2048)
    gemm_bt<ushort, ushort><<<dim3(8, 64, 1), 256, 0, stream>>>(
        mem_bf, WkT, Kp, 1024, 1024, 1024, 1024, 1, 0, 0, 0, 0, 0, 0, 1.0f);
    gemm_bt<ushort, ushort><<<dim3(8, 64, 1), 256, 0, stream>>>(
        mem_bf, WvT, Vp, 1024, 1024, 1024, 1024, 1, 0, 0, 0, 0, 0, 0, 1.0f);
    gemm_bt<ushort, ushort><<<dim3(8, 64, 1), 256, 0, stream>>>(
        concat, WqT, Qp, 1024, 2048, 1024, 1024, 1, 0, 0, 0, 0, 0, 0, 1.0f);
    // 4) V transpose per (b,h)
    vtrans<<<dim3(32, 4, 64), dim3(32, 8), 0, stream>>>(Vp, VT);
    // 5) scores = Q K^T / sqrt(dh): z = h*8+b (z/8=h, z%8=b)
    gemm_bt<ushort, float><<<dim3(8, 8, 64), 256, 0, stream>>>(
        Qp, Kp, attns, 128, 1024, 1024, 1024, 8,
        128LL, 1048576LL,      // A: h-stride 128, b-stride 1M
        128LL, 1048576LL,      // B: same
        8388608LL, 1048576LL,  // C: h-stride 8M, b-stride 1M
        alpha_s);
    // 6) masked softmax * query_mask (in place)
    softmax_qm<<<65536, 256, 0, stream>>>(attns, mask, qmask);
    // 7) x_att = attn @ V -> concat right half: z = b*8+h (z/8=b, z%8=h)
    gemm_bt<float, ushort><<<dim3(1, 8, 64), 256, 0, stream>>>(
        attns, VT, concat + 1024, 1024, 1024, 1024, 2048, 8,
        1048576LL, 8388608LL,  // A: b-stride 1M, h-stride 8M
        131072LL, 1048576LL,   // B(VT): b-stride 128K, h-stride 1M
        2097152LL, 128LL,      // C: b-stride 2M, h-stride 128
        1.0f);
    // 8) FFN: concat(8192x2048) @ WfT^T -> ffn fp32
    gemm_bt<ushort, float><<<dim3(8, 64, 1), 256, 0, stream>>>(
        concat, WfT, ffn, 2048, 2048, 2048, 1024, 1, 0, 0, 0, 0, 0, 0, 1.0f);
    // 9) bias + residual + LayerNorm -> x output
    ln_out<<<8192, 256, 0, stream>>>(ffn, decoder, bfv, gamma, beta, xout);
}

// Round 3
// 708.050 us; speedup vs baseline: 1.0860x; 1.0860x over previous
//
#include <hip/hip_runtime.h>
#include <hip/hip_bf16.h>
#include <stdint.h>

typedef __attribute__((ext_vector_type(4))) float  floatx4;
typedef __attribute__((ext_vector_type(8))) short  shortx8;

__device__ __forceinline__ unsigned short f2bf(float f) {
    unsigned int u = __builtin_bit_cast(unsigned int, f);
    u += 0x7FFFu + ((u >> 16) & 1u);
    return (unsigned short)(u >> 16);
}
__device__ __forceinline__ float bf2f(unsigned short h) {
    unsigned int u = (unsigned int)h << 16;
    return __builtin_bit_cast(float, u);
}

__device__ __forceinline__ uint4 pack8(float4 a, float4 b) {
    uint4 r;
    r.x = (unsigned)f2bf(a.x) | ((unsigned)f2bf(a.y) << 16);
    r.y = (unsigned)f2bf(a.z) | ((unsigned)f2bf(a.w) << 16);
    r.z = (unsigned)f2bf(b.x) | ((unsigned)f2bf(b.y) << 16);
    r.w = (unsigned)f2bf(b.z) | ((unsigned)f2bf(b.w) << 16);
    return r;
}

// ---------------- cast kernels ----------------
__global__ __launch_bounds__(256) void cast_bf16(const float* __restrict__ src,
                                                 ushort* __restrict__ dst) {
    long long i = ((long long)blockIdx.x * 256 + threadIdx.x) * 8;
    const float4* p = (const float4*)(src + i);
    float4 f0 = p[0], f1 = p[1];
    *(uint4*)(dst + i) = pack8(f0, f1);
}

// decoder (8192x1024 fp32) -> concat left half (row stride 2048, bf16)
__global__ __launch_bounds__(256) void cast_stride(const float* __restrict__ src,
                                                   ushort* __restrict__ dst) {
    long long i = ((long long)blockIdx.x * 256 + threadIdx.x) * 8;
    long long r = i >> 10, c = i & 1023;
    const float4* p = (const float4*)(src + i);
    float4 f0 = p[0], f1 = p[1];
    *(uint4*)(dst + r * 2048 + c) = pack8(f0, f1);
}

// ---------------- weight transpose-cast: W[K][N] fp32 -> WT[N][K] bf16 ----------------
__global__ __launch_bounds__(256) void wtrans(const float* __restrict__ W,
                                              ushort* __restrict__ WT, int K, int N) {
    __shared__ float t[32][33];
    int tx = threadIdx.x, ty = threadIdx.y;
    int bx = blockIdx.x * 32;  // n
    int by = blockIdx.y * 32;  // k
    #pragma unroll
    for (int i = 0; i < 4; i++)
        t[ty + 8 * i][tx] = W[(size_t)(by + ty + 8 * i) * N + bx + tx];
    __syncthreads();
    #pragma unroll
    for (int i = 0; i < 4; i++)
        WT[(size_t)(bx + ty + 8 * i) * K + by + tx] = f2bf(t[tx][ty + 8 * i]);
}

// ---------------- V transpose per (b,h): V[(b*1024+k)*1024+h*128+d] -> VT[((h*8+b)*128+d)*1024+k]
__global__ __launch_bounds__(256) void vtrans(const ushort* __restrict__ V,
                                              ushort* __restrict__ VT) {
    __shared__ ushort t[32][33];
    int tx = threadIdx.x, ty = threadIdx.y;
    int bk = blockIdx.x * 32;  // k
    int bd = blockIdx.y * 32;  // d
    int z = blockIdx.z;
    int b = z >> 3, h = z & 7;
    #pragma unroll
    for (int i = 0; i < 4; i++)
        t[ty + 8 * i][tx] = V[((size_t)(b * 1024 + bk + ty + 8 * i)) * 1024 + h * 128 + bd + tx];
    __syncthreads();
    #pragma unroll
    for (int i = 0; i < 4; i++)
        VT[((size_t)((h * 8 + b) * 128 + bd + ty + 8 * i)) * 1024 + bk + tx] = t[tx][ty + 8 * i];
}

// ---------------- GEMM: C[m][n] = sum_k A[m][k] * Bt[n][k] (bf16 in, bf16/fp32 out) ----
template <typename TC>
__global__ __launch_bounds__(256) void gemm_bt(
    const ushort* __restrict__ A, const ushort* __restrict__ Bt, TC* __restrict__ C,
    int K, int lda, int ldb, int ldc) {
    constexpr int LS = 72;
    __shared__ ushort As[128 * LS];
    __shared__ ushort Bs[128 * LS];

    int tid = threadIdx.x;
    int bm = blockIdx.y * 128, bn = blockIdx.x * 128;
    int l = tid & 63, wid = tid >> 6;
    int l16 = l & 15, quad = l >> 4;
    int wm = (wid & 1) * 64, wn = (wid >> 1) * 64;

    floatx4 acc[4][4];
    #pragma unroll
    for (int i = 0; i < 4; i++)
        #pragma unroll
        for (int j = 0; j < 4; j++)
            acc[i][j] = {0.0f, 0.0f, 0.0f, 0.0f};

    for (int kt = 0; kt < K; kt += 64) {
        #pragma unroll
        for (int it = 0; it < 4; it++) {
            int lin = it * 256 + tid;
            int row = lin >> 3, col = (lin & 7) << 3;
            uint4 av = *(const uint4*)(A + (size_t)(bm + row) * lda + kt + col);
            *(uint4*)&As[row * LS + col] = av;
            uint4 bv = *(const uint4*)(Bt + (size_t)(bn + row) * ldb + kt + col);
            *(uint4*)&Bs[row * LS + col] = bv;
        }
        __syncthreads();
        #pragma unroll
        for (int kk = 0; kk < 64; kk += 32) {
            shortx8 af[4], bfr[4];
            #pragma unroll
            for (int i = 0; i < 4; i++)
                af[i] = *(const shortx8*)&As[(wm + i * 16 + l16) * LS + kk + quad * 8];
            #pragma unroll
            for (int j = 0; j < 4; j++)
                bfr[j] = *(const shortx8*)&Bs[(wn + j * 16 + l16) * LS + kk + quad * 8];
            #pragma unroll
            for (int i = 0; i < 4; i++)
                #pragma unroll
                for (int j = 0; j < 4; j++)
                    acc[i][j] = __builtin_amdgcn_mfma_f32_16x16x32_bf16(af[i], bfr[j], acc[i][j], 0, 0, 0);
        }
        __syncthreads();
    }

    #pragma unroll
    for (int i = 0; i < 4; i++) {
        #pragma unroll
        for (int j = 0; j < 4; j++) {
            int row0 = bm + wm + i * 16 + quad * 4;
            int col = bn + wn + j * 16 + l16;
            #pragma unroll
            for (int r = 0; r < 4; r++) {
                float v = acc[i][j][r];
                size_t idx = (size_t)(row0 + r) * ldc + col;
                if constexpr (__is_same(TC, float)) C[idx] = v;
                else C[idx] = f2bf(v);
            }
        }
    }
}

// ---------------- fused attention: QK^T -> mask -> softmax -> *qmask -> attns + PV ------
// One block = 16 Q-rows of one (h,b). Full exp'd score row kept in LDS (bf16).
// No max-subtraction (scores bounded; exp fits fp32 easily; masked -> exact 0).
// K/V staged in per-wave-private LDS regions => no barriers inside MFMA loops.
// `concat` param is the BASE of the concat buffer; right-half offset applied inside.
__global__ __launch_bounds__(256) void fused_attn(
    const ushort* __restrict__ Qp, const ushort* __restrict__ Kp,
    const ushort* __restrict__ VT, const int* __restrict__ mask,
    const float* __restrict__ qmask, float* __restrict__ attns,
    ushort* __restrict__ concat) {
    __shared__ ushort Qs[16 * 136];        // Q tile
    __shared__ ushort Kv[4 * 2304];        // per-wave: QK: 16x136; PV: 32x72
    __shared__ ushort Ss[16 * 1032];       // exp'd scores bf16, stride 1032 (pad 8)
    __shared__ float rowpart[16][17];
    __shared__ float scale_s[16];

    const int b = blockIdx.z, h = blockIdx.y, q0 = blockIdx.x * 16;
    const int tid = threadIdx.x;
    const int w = tid >> 6, l = tid & 63;
    const int l16 = l & 15, quad = l >> 4;
    const float sc = 0.08838834764831845f;  // 1/sqrt(128)

    // ---- load Q tile (16 x 128) ----
    {
        int row = tid >> 4, col = (tid & 15) * 8;
        *(uint4*)&Qs[row * 136 + col] =
            *(const uint4*)(Qp + (size_t)(b * 1024 + q0 + row) * 1024 + h * 128 + col);
    }
    __syncthreads();

    // preload A-fragments (reused for all k-tiles)
    shortx8 af[4];
    #pragma unroll
    for (int kk = 0; kk < 4; kk++)
        af[kk] = *(const shortx8*)&Qs[l16 * 136 + kk * 32 + quad * 8];

    // ---- QK^T + mask + exp, per-wave private staging (no barriers) ----
    ushort* Ksw = &Kv[w * 2304];
    const size_t mbase = (size_t)b * 1048576 + (size_t)q0 * 1024;
    for (int c = 0; c < 16; ++c) {
        int k0 = c * 64 + w * 16;  // this wave's 16 K-rows
        #pragma unroll
        for (int i = 0; i < 4; ++i) {
            int lin = i * 64 + l;
            int kr = lin >> 4, col = (lin & 15) * 8;
            *(uint4*)&Ksw[kr * 136 + col] =
                *(const uint4*)(Kp + (size_t)(b * 1024 + k0 + kr) * 1024 + h * 128 + col);
        }
        floatx4 acc = {0.0f, 0.0f, 0.0f, 0.0f};
        #pragma unroll
        for (int kk = 0; kk < 4; ++kk) {
            shortx8 bfr = *(const shortx8*)&Ksw[l16 * 136 + kk * 32 + quad * 8];
            acc = __builtin_amdgcn_mfma_f32_16x16x32_bf16(af[kk], bfr, acc, 0, 0, 0);
        }
        #pragma unroll
        for (int r = 0; r < 4; ++r) {
            int q = quad * 4 + r;
            int m = mask[mbase + (size_t)q * 1024 + k0 + l16];
            float v = m ? 0.0f : __expf(acc[r] * sc);
            Ss[q * 1032 + k0 + l16] = f2bf(v);
        }
    }
    __syncthreads();

    // ---- row sums ----
    {
        int row = tid >> 4, cs = (tid & 15) * 64;
        float s = 0.0f;
        #pragma unroll
        for (int i = 0; i < 8; ++i) {
            shortx8 v = *(const shortx8*)&Ss[row * 1032 + cs + i * 8];
            #pragma unroll
            for (int j = 0; j < 8; ++j) s += bf2f((unsigned short)v[j]);
        }
        rowpart[row][tid & 15] = s;
    }
    __syncthreads();
    if (tid < 16) {
        float s = 0.0f;
        #pragma unroll
        for (int i = 0; i < 16; ++i) s += rowpart[tid][i];
        scale_s[tid] = qmask[b * 1024 + q0 + tid] / s;
    }
    __syncthreads();

    // ---- write normalized attns (fp32, includes qmask) ----
    {
        int row = tid >> 4;
        float scl = scale_s[row];
        float* arow = attns + ((size_t)((h * 8 + b) * 1024 + q0 + row)) * 1024;
        int c0 = (tid & 15) * 4;
        #pragma unroll
        for (int j = 0; j < 16; ++j) {
            int c = c0 + j * 64;
            ushort4 v = *(const ushort4*)&Ss[row * 1032 + c];
            float4 o;
            o.x = bf2f(v.x) * scl;
            o.y = bf2f(v.y) * scl;
            o.z = bf2f(v.z) * scl;
            o.w = bf2f(v.w) * scl;
            *(float4*)(arow + c) = o;
        }
    }

    // ---- PV: O = P @ V, per-wave private V staging (no barriers) ----
    ushort* Vsw = &Kv[w * 2304];  // 32 x 72
    const ushort* Vb = VT + (size_t)((h * 8 + b) * 128 + w * 32) * 1024;
    floatx4 oacc[2] = {{0.0f, 0.0f, 0.0f, 0.0f}, {0.0f, 0.0f, 0.0f, 0.0f}};
    for (int c = 0; c < 16; ++c) {
        #pragma unroll
        for (int i = 0; i < 4; ++i) {
            int lin = i * 64 + l;
            int dr = lin >> 3, ko = (lin & 7) * 8;
            *(uint4*)&Vsw[dr * 72 + ko] =
                *(const uint4*)(Vb + (size_t)dr * 1024 + c * 64 + ko);
        }
        #pragma unroll
        for (int ks = 0; ks < 2; ++ks) {
            shortx8 a = *(const shortx8*)&Ss[l16 * 1032 + c * 64 + ks * 32 + quad * 8];
            #pragma unroll
            for (int j = 0; j < 2; ++j) {
                shortx8 bfr = *(const shortx8*)&Vsw[(j * 16 + l16) * 72 + ks * 32 + quad * 8];
                oacc[j] = __builtin_amdgcn_mfma_f32_16x16x32_bf16(a, bfr, oacc[j], 0, 0, 0);
            }
        }
    }
    #pragma unroll
    for (int j = 0; j < 2; ++j) {
        #pragma unroll
        for (int r = 0; r < 4; ++r) {
            int q = quad * 4 + r;
            int d = w * 32 + j * 16 + l16;
            float v = oacc[j][r] * scale_s[q];
            concat[(size_t)(b * 1024 + q0 + q) * 2048 + 1024 + h * 128 + d] = f2bf(v);
        }
    }
}

// ---------------- LayerNorm epilogue: x = LN(ffn + bf + decoder) ----------------
__global__ __launch_bounds__(256) void ln_out(const float* __restrict__ ffn,
                                              const float* __restrict__ dec,
                                              const float* __restrict__ bfv,
                                              const float* __restrict__ gamma,
                                              const float* __restrict__ beta,
                                              float* __restrict__ out) {
    __shared__ float sb[8];
    int row = blockIdx.x, tid = threadIdx.x;
    int c = tid * 4;
    size_t base = (size_t)row * 1024 + c;
    float4 x = *(const float4*)(ffn + base);
    float4 d = *(const float4*)(dec + base);
    float4 bb = *(const float4*)(bfv + c);
    x.x += d.x + bb.x; x.y += d.y + bb.y; x.z += d.z + bb.z; x.w += d.w + bb.w;

    float s = x.x + x.y + x.z + x.w;
    float s2 = x.x * x.x + x.y * x.y + x.z * x.z + x.w * x.w;
    #pragma unroll
    for (int o = 32; o; o >>= 1) {
        s += __shfl_down(s, o, 64);
        s2 += __shfl_down(s2, o, 64);
    }
    if ((tid & 63) == 0) { sb[tid >> 6] = s; sb[4 + (tid >> 6)] = s2; }
    __syncthreads();
    s = sb[0] + sb[1] + sb[2] + sb[3];
    s2 = sb[4] + sb[5] + sb[6] + sb[7];
    float mu = s * (1.0f / 1024.0f);
    float var = s2 * (1.0f / 1024.0f) - mu * mu;
    float rs = rsqrtf(var + 1e-5f);

    float4 g = *(const float4*)(gamma + c);
    float4 be = *(const float4*)(beta + c);
    float4 o4;
    o4.x = (x.x - mu) * rs * g.x + be.x;
    o4.y = (x.y - mu) * rs * g.y + be.y;
    o4.z = (x.z - mu) * rs * g.z + be.z;
    o4.w = (x.w - mu) * rs * g.w + be.w;
    *(float4*)(out + base) = o4;
}

extern "C" void kernel_launch(void* const* d_in, const int* in_sizes, int n_in,
                              void* d_out, int out_size, void* d_ws, size_t ws_size,
                              hipStream_t stream) {
    const float* memory  = (const float*)d_in[0];   // (8,1024,1024)
    const float* decoder = (const float*)d_in[1];   // (8,1024,1024)
    const float* qmask   = (const float*)d_in[2];   // (8,1024)
    const float* Wk      = (const float*)d_in[3];   // (1024,1024)
    const float* Wv      = (const float*)d_in[4];
    const float* Wq      = (const float*)d_in[5];
    const float* Wf      = (const float*)d_in[6];   // (2048,1024)
    const float* bfv     = (const float*)d_in[7];   // (1024,)
    const float* gamma   = (const float*)d_in[8];
    const float* beta    = (const float*)d_in[9];
    const int*   mask    = (const int*)d_in[10];    // (8,1024,1024) 0/1

    float* xout  = (float*)d_out;                   // (8,1024,1024)
    float* attns = xout + 8388608LL;                // (64,1024,1024)

    char* w = (char*)d_ws;
    ushort* mem_bf = (ushort*)(w + 0);              // 16 MB (dead after projections)
    ushort* Kp     = (ushort*)(w + (16LL << 20));   // 16 MB (dead after fused_attn)
    float*  ffn    = (float*)(w + 0);               // 32 MB, written after Kp dead
    ushort* Qp     = (ushort*)(w + (32LL << 20));   // 16 MB
    ushort* Vp     = (ushort*)(w + (48LL << 20));   // 16 MB
    ushort* VT     = (ushort*)(w + (64LL << 20));   // 16 MB
    ushort* concat = (ushort*)(w + (80LL << 20));   // 32 MB (8192 x 2048 bf16)
    ushort* WkT    = (ushort*)(w + (112LL << 20));  // 2 MB
    ushort* WvT    = (ushort*)(w + (114LL << 20));  // 2 MB
    ushort* WqT    = (ushort*)(w + (116LL << 20));  // 2 MB
    ushort* WfT    = (ushort*)(w + (118LL << 20));  // 4 MB

    // 1) casts
    cast_bf16<<<4096, 256, 0, stream>>>(memory, mem_bf);
    cast_stride<<<4096, 256, 0, stream>>>(decoder, concat);
    // 2) weight transposes
    wtrans<<<dim3(32, 32), dim3(32, 8), 0, stream>>>(Wk, WkT, 1024, 1024);
    wtrans<<<dim3(32, 32), dim3(32, 8), 0, stream>>>(Wv, WvT, 1024, 1024);
    wtrans<<<dim3(32, 32), dim3(32, 8), 0, stream>>>(Wq, WqT, 1024, 1024);
    wtrans<<<dim3(32, 64), dim3(32, 8), 0, stream>>>(Wf, WfT, 2048, 1024);
    // 3) projections
    gemm_bt<ushort><<<dim3(8, 64), 256, 0, stream>>>(mem_bf, WkT, Kp, 1024, 1024, 1024, 1024);
    gemm_bt<ushort><<<dim3(8, 64), 256, 0, stream>>>(mem_bf, WvT, Vp, 1024, 1024, 1024, 1024);
    gemm_bt<ushort><<<dim3(8, 64), 256, 0, stream>>>(concat, WqT, Qp, 1024, 2048, 1024, 1024);
    // 4) V transpose per (b,h)
    vtrans<<<dim3(32, 4, 64), dim3(32, 8), 0, stream>>>(Vp, VT);
    // 5) fused QK^T+softmax+qmask -> attns, and PV -> concat right half
    //    NOTE: pass concat BASE; right-half (+1024) offset is applied inside the kernel.
    fused_attn<<<dim3(64, 8, 8), 256, 0, stream>>>(Qp, Kp, VT, mask, qmask, attns, concat);
    // 6) FFN: concat(8192x2048) @ WfT^T -> ffn fp32
    gemm_bt<float><<<dim3(8, 64), 256, 0, stream>>>(concat, WfT, ffn, 2048, 2048, 2048, 1024);
    // 7) bias + residual + LayerNorm -> x output
    ln_out<<<8192, 256, 0, stream>>>(ffn, decoder, bfv, gamma, beta, xout);
}